// Round 18
// baseline (206.059 us; speedup 1.0000x reference)
//
#include <hip/hip_runtime.h>
#include <hip/hip_bf16.h>
#include <math.h>

#define M_TOT 8192
#define D_DIM 1024
#define E_NUM 8
#define P_DIM 1024
#define K_TOT (E_NUM * D_DIM)  // 8192

typedef __attribute__((ext_vector_type(8))) short short8;
typedef __attribute__((ext_vector_type(4))) float f32x4;
typedef __attribute__((ext_vector_type(8))) unsigned short u16x8;

// round-to-nearest-even f32 -> bf16 (finite inputs)
static __device__ __forceinline__ unsigned short f2bf(float f) {
  unsigned u = __builtin_bit_cast(unsigned, f);
  unsigned r = (u + 0x7fffu + ((u >> 16) & 1u)) >> 16;
  return (unsigned short)r;
}

static __device__ __forceinline__ short8 ldfrag(const unsigned short* buf, int row, int e0) {
  return *reinterpret_cast<const short8*>(&buf[row * 64 + (e0 ^ ((row & 7) << 3))]);
}

// ---- merged prep: blocks [0,2048) = per-row gate+xb+bias-init; [2048,4096) = W-transpose tiles ----
__global__ __launch_bounds__(256) void prep_all_kernel(const float* __restrict__ x,
                                                       const float* __restrict__ gw,
                                                       const float* __restrict__ gb,
                                                       const float* __restrict__ ew,
                                                       const float* __restrict__ eb,
                                                       float* __restrict__ gate,
                                                       unsigned short* __restrict__ xb,
                                                       unsigned short* __restrict__ wt,
                                                       float* __restrict__ out) {
  __shared__ __align__(16) unsigned short lx[4][1024];  // 8 KB   (prep path)
  __shared__ float tile[64][65];                        // 16.25 KB (wtrans path)

  if (blockIdx.x < 2048) {
    const int wv   = threadIdx.x >> 6;
    const int lane = threadIdx.x & 63;
    const int row  = blockIdx.x * 4 + wv;
    const float* xr = x + (size_t)row * D_DIM;

    float acc[E_NUM];
#pragma unroll
    for (int e = 0; e < E_NUM; ++e) acc[e] = 0.f;
#pragma unroll
    for (int it = 0; it < 16; ++it) {
      const int d = it * 64 + lane;
      const float xv = xr[d];
      lx[wv][d] = f2bf(xv);
      const float4* g4 = reinterpret_cast<const float4*>(gw + (size_t)d * E_NUM);
      const float4 a = g4[0], b = g4[1];
      acc[0] += xv * a.x; acc[1] += xv * a.y; acc[2] += xv * a.z; acc[3] += xv * a.w;
      acc[4] += xv * b.x; acc[5] += xv * b.y; acc[6] += xv * b.z; acc[7] += xv * b.w;
    }
#pragma unroll
    for (int off = 32; off >= 1; off >>= 1) {
#pragma unroll
      for (int e = 0; e < E_NUM; ++e) acc[e] += __shfl_xor(acc[e], off, 64);
    }
    __syncthreads();

    float g[E_NUM], mx = -1e30f;
#pragma unroll
    for (int e = 0; e < E_NUM; ++e) { g[e] = acc[e] + gb[e]; mx = fmaxf(mx, g[e]); }
    float s = 0.f;
#pragma unroll
    for (int e = 0; e < E_NUM; ++e) { g[e] = expf(g[e] - mx); s += g[e]; }
    const float inv = 1.f / s;
#pragma unroll
    for (int e = 0; e < E_NUM; ++e) g[e] *= inv;
    if (lane == 0) {
#pragma unroll
      for (int e = 0; e < E_NUM; ++e) gate[(size_t)row * E_NUM + e] = g[e];
    }

    unsigned short* xrow = xb + (size_t)row * D_DIM;
#pragma unroll
    for (int h = 0; h < 2; ++h) {
      const int jd = lane * 2 + h;
      const int cbase = (jd >> 3) * 8 + ((jd & 7) ^ (row & 7));
      const u16x8 vv = *reinterpret_cast<const u16x8*>(&lx[wv][jd * 8]);
      *reinterpret_cast<u16x8*>(&xrow[cbase * 8]) = vv;
    }

    float* orow = out + (size_t)row * P_DIM;
#pragma unroll
    for (int q = 0; q < 4; ++q) {
      const int p = q * 256 + lane * 4;
      float4 sv = {0.f, 0.f, 0.f, 0.f};
#pragma unroll
      for (int e = 0; e < E_NUM; ++e) {
        const float4 b4 = *reinterpret_cast<const float4*>(&eb[(size_t)e * P_DIM + p]);
        sv.x += g[e] * b4.x; sv.y += g[e] * b4.y; sv.z += g[e] * b4.z; sv.w += g[e] * b4.w;
      }
      *reinterpret_cast<float4*>(&orow[p]) = sv;
    }
  } else {
    const int bid2 = blockIdx.x - 2048;
    const int e  = bid2 >> 8;
    const int p0 = ((bid2 >> 4) & 15) * 64;
    const int d0 = (bid2 & 15) * 64;
    const int tx = threadIdx.x & 63;
    const int ty = threadIdx.x >> 6;
    const float* src = ew + ((size_t)e * D_DIM + d0) * P_DIM + p0;
#pragma unroll
    for (int i = 0; i < 16; ++i) {
      const int dr = i * 4 + ty;
      tile[dr][tx] = src[(size_t)dr * P_DIM + tx];
    }
    __syncthreads();
#pragma unroll
    for (int h = 0; h < 2; ++h) {
      const int u  = threadIdx.x + h * 256;
      const int pr = u >> 3;
      const int ch = u & 7;
      u16x8 v;
#pragma unroll
      for (int j = 0; j < 8; ++j) v[j] = f2bf(tile[ch * 8 + j][pr]);
      const int cs = ch ^ (pr & 7);
      *reinterpret_cast<u16x8*>(&wt[(size_t)(p0 + pr) * K_TOT + e * D_DIM + d0 + cs * 8]) = v;
    }
  }
}

// ---- 8-phase 256x256 GEMM: BK=64, 8 waves (2Mx4N, 128x64/wave), counted vmcnt(4)/tile.
// Split-K=2 over expert halves; Horner rescale every 16 tiles. Derived schedule:
//   invariant entering tile t: tile t resident in buf[t&1]; A0(t+1),A1(t+1) in flight.
//   ph1: ds A-lo(8)+B-lo(4); stage B0(t+1)    [buf t+1, sealed end t-1]  -> MFMA (m-lo,n-lo)
//   ph2: ds A-hi(8);         stage B1(t+1)                               -> MFMA (m-hi,n-lo)
//   ph3: ds B-hi(4);         stage A0(t+2)    [buf t; A-reads done ph2]  -> MFMA (m-lo,n-hi)
//   ph4:                     stage A1(t+2)                               -> MFMA (m-hi,n-hi)
//   vmcnt(4) retires A0,A1,B0,B1(t+1) (issue-order oldest 8), keeps A(t+2) in flight.
__global__ __launch_bounds__(512, 1) void gemm_8ph_kernel(
    const unsigned short* __restrict__ xb,
    const unsigned short* __restrict__ wt,
    const float* __restrict__ gate,
    float* __restrict__ out) {
  __shared__ __align__(16) unsigned short lA[2 * 256 * 64];  // 64 KB
  __shared__ __align__(16) unsigned short lB[2 * 256 * 64];  // 64 KB
  __shared__ float lG[256 * 8];                              // 8 KB -> 136 KB

  const int tid  = threadIdx.x;
  const int lane = tid & 63;
  const int wid  = tid >> 6;
  const int wm   = wid >> 2;   // 0..1: rows [wm*128, wm*128+128)
  const int wn   = wid & 3;    // 0..3: cols [wn*64, wn*64+64)
  const int l15  = lane & 15;
  const int e0b  = (lane >> 4) * 8;

  // 256 blocks: xcd = bid&7 = nt*2+kh (B slice 2MB L2-resident); mt = bid>>3.
  const int bid = blockIdx.x;
  const int xcd = bid & 7;
  const int nt  = xcd >> 1;
  const int kh  = xcd & 1;
  const int mt  = bid >> 3;
  const int m0  = mt * 256, n0 = nt * 256;

  // gate tile [256][8] -> LDS; syncthreads drains vmcnt so counted staging starts clean.
  reinterpret_cast<float4*>(lG)[tid] =
      reinterpret_cast<const float4*>(gate + (size_t)m0 * E_NUM)[tid];
  __syncthreads();

  auto stA = [&](int t, int h) {
    const int tw = t & 63, b = t & 1;
    const int ko = (tw & 15) * 64;  // xb row is 1024 wide; repeats per expert
#pragma unroll
    for (int l = 0; l < 2; ++l) {
      const int u = tid + l * 512;
      const int row = u >> 3, ch = u & 7;
      const unsigned short* src = xb + (size_t)(m0 + h * 128 + row) * D_DIM + ko + ch * 8;
      __builtin_amdgcn_global_load_lds(
          (const __attribute__((address_space(1))) void*)src,
          (__attribute__((address_space(3))) void*)&lA[b * 16384 + (h * 128 + row) * 64 + ch * 8],
          16, 0, 0);
    }
  };
  auto stB = [&](int t, int h) {
    const int tw = t & 63, b = t & 1;
    const size_t ko = ((size_t)kh * 64 + tw) * 64;
#pragma unroll
    for (int l = 0; l < 2; ++l) {
      const int u = tid + l * 512;
      const int row = u >> 3, ch = u & 7;
      const unsigned short* src = wt + (size_t)(n0 + h * 128 + row) * K_TOT + ko + ch * 8;
      __builtin_amdgcn_global_load_lds(
          (const __attribute__((address_space(1))) void*)src,
          (__attribute__((address_space(3))) void*)&lB[b * 16384 + (h * 128 + row) * 64 + ch * 8],
          16, 0, 0);
    }
  };

  f32x4 acc[8][4];
#pragma unroll
  for (int i = 0; i < 8; ++i)
#pragma unroll
    for (int j = 0; j < 4; ++j)
#pragma unroll
      for (int k = 0; k < 4; ++k) acc[i][j][k] = 0.f;

  // prologue: tile0 (A0,A1,B0,B1) + A(1) -> 12 loads; retire tile0's 8.
  stA(0, 0); stA(0, 1); stB(0, 0); stB(0, 1);
  stA(1, 0); stA(1, 1);
  asm volatile("s_waitcnt vmcnt(4)" ::: "memory");
  __builtin_amdgcn_s_barrier();
  asm volatile("" ::: "memory");

#pragma unroll 1
  for (int t = 0; t < 64; ++t) {
    const int b = t & 1;
    const unsigned short* bufA = lA + b * 16384;
    const unsigned short* bufB = lB + b * 16384;

    if ((t & 15) == 0 && t > 0) {
      const int eg = kh * 4 + (t >> 4);  // entering expert eg; rescale by g[eg-1]/g[eg]
#pragma unroll
      for (int mf = 0; mf < 8; ++mf) {
#pragma unroll
        for (int reg = 0; reg < 4; ++reg) {
          const int r = wm * 128 + mf * 16 + (lane >> 4) * 4 + reg;
          const float ratio = lG[r * 8 + (eg - 1)] / lG[r * 8 + eg];
#pragma unroll
          for (int nf = 0; nf < 4; ++nf) acc[mf][nf][reg] *= ratio;
        }
      }
    }

    short8 a0[4][2], a1[4][2], b0[2][2], b1[2][2];

    // ================= PH1: (m-lo, n-lo) =================
#pragma unroll
    for (int mf = 0; mf < 4; ++mf)
#pragma unroll
      for (int kk = 0; kk < 2; ++kk)
        a0[mf][kk] = ldfrag(bufA, wm * 128 + mf * 16 + l15, kk * 32 + e0b);
#pragma unroll
    for (int nf = 0; nf < 2; ++nf)
#pragma unroll
      for (int kk = 0; kk < 2; ++kk)
        b0[nf][kk] = ldfrag(bufB, wn * 64 + nf * 16 + l15, kk * 32 + e0b);
    stB(t + 1, 0);
    __builtin_amdgcn_s_barrier();
    asm volatile("s_waitcnt lgkmcnt(0)" ::: "memory");
    __builtin_amdgcn_s_setprio(1);
#pragma unroll
    for (int mf = 0; mf < 4; ++mf)
#pragma unroll
      for (int nf = 0; nf < 2; ++nf)
#pragma unroll
        for (int kk = 0; kk < 2; ++kk)
          acc[mf][nf] = __builtin_amdgcn_mfma_f32_16x16x32_bf16(a0[mf][kk], b0[nf][kk], acc[mf][nf], 0, 0, 0);
    __builtin_amdgcn_s_setprio(0);
    __builtin_amdgcn_s_barrier();
    asm volatile("" ::: "memory");

    // ================= PH2: (m-hi, n-lo) =================
#pragma unroll
    for (int mf = 0; mf < 4; ++mf)
#pragma unroll
      for (int kk = 0; kk < 2; ++kk)
        a1[mf][kk] = ldfrag(bufA, wm * 128 + 64 + mf * 16 + l15, kk * 32 + e0b);
    stB(t + 1, 1);
    __builtin_amdgcn_s_barrier();
    asm volatile("s_waitcnt lgkmcnt(0)" ::: "memory");
    __builtin_amdgcn_s_setprio(1);
#pragma unroll
    for (int mf = 0; mf < 4; ++mf)
#pragma unroll
      for (int nf = 0; nf < 2; ++nf)
#pragma unroll
        for (int kk = 0; kk < 2; ++kk)
          acc[4 + mf][nf] = __builtin_amdgcn_mfma_f32_16x16x32_bf16(a1[mf][kk], b0[nf][kk], acc[4 + mf][nf], 0, 0, 0);
    __builtin_amdgcn_s_setprio(0);
    __builtin_amdgcn_s_barrier();
    asm volatile("" ::: "memory");

    // ================= PH3: (m-lo, n-hi) =================
#pragma unroll
    for (int nf = 0; nf < 2; ++nf)
#pragma unroll
      for (int kk = 0; kk < 2; ++kk)
        b1[nf][kk] = ldfrag(bufB, wn * 64 + 32 + nf * 16 + l15, kk * 32 + e0b);
    stA(t + 2, 0);  // A-reads of tile t completed by ph2's lgkmcnt+barrier
    __builtin_amdgcn_s_barrier();
    asm volatile("s_waitcnt lgkmcnt(0)" ::: "memory");
    __builtin_amdgcn_s_setprio(1);
#pragma unroll
    for (int mf = 0; mf < 4; ++mf)
#pragma unroll
      for (int nf = 0; nf < 2; ++nf)
#pragma unroll
        for (int kk = 0; kk < 2; ++kk)
          acc[mf][2 + nf] = __builtin_amdgcn_mfma_f32_16x16x32_bf16(a0[mf][kk], b1[nf][kk], acc[mf][2 + nf], 0, 0, 0);
    __builtin_amdgcn_s_setprio(0);
    __builtin_amdgcn_s_barrier();
    asm volatile("" ::: "memory");

    // ================= PH4: (m-hi, n-hi) =================
    stA(t + 2, 1);
    __builtin_amdgcn_s_setprio(1);
#pragma unroll
    for (int mf = 0; mf < 4; ++mf)
#pragma unroll
      for (int nf = 0; nf < 2; ++nf)
#pragma unroll
        for (int kk = 0; kk < 2; ++kk)
          acc[4 + mf][2 + nf] = __builtin_amdgcn_mfma_f32_16x16x32_bf16(a1[mf][kk], b1[nf][kk], acc[4 + mf][2 + nf], 0, 0, 0);
    __builtin_amdgcn_s_setprio(0);
    asm volatile("s_waitcnt vmcnt(4)" ::: "memory");  // tile t+1 fully resident; A(t+2) stays in flight
    __builtin_amdgcn_s_barrier();
    asm volatile("" ::: "memory");
  }

  // ---- epilogue: final Horner scale by g[row][kh*4+3]; atomic accumulate (bias pre-init) ----
#pragma unroll
  for (int nf = 0; nf < 4; ++nf) {
    const int cl = n0 + wn * 64 + nf * 16 + l15;
#pragma unroll
    for (int mf = 0; mf < 8; ++mf) {
#pragma unroll
      for (int reg = 0; reg < 4; ++reg) {
        const int r = wm * 128 + mf * 16 + (lane >> 4) * 4 + reg;
        const float gl = lG[r * 8 + kh * 4 + 3];
        atomicAdd(&out[(size_t)(m0 + r) * P_DIM + cl], acc[mf][nf][reg] * gl);
      }
    }
  }
}

// ============================ FALLBACK PATH (round-2, passing) ============================

__global__ __launch_bounds__(256) void gate_kernel(const float* __restrict__ x,
                                                   const float* __restrict__ gw,
                                                   const float* __restrict__ gb,
                                                   float* __restrict__ gate) {
  const int row  = blockIdx.x * 4 + (threadIdx.x >> 6);
  const int lane = threadIdx.x & 63;
  const float* xr = x + (size_t)row * D_DIM;
  float acc[E_NUM];
#pragma unroll
  for (int e = 0; e < E_NUM; ++e) acc[e] = 0.f;
#pragma unroll
  for (int it = 0; it < 16; ++it) {
    const int d = it * 64 + lane;
    const float xv = xr[d];
    const float4* g4 = reinterpret_cast<const float4*>(gw + (size_t)d * E_NUM);
    float4 a = g4[0], b = g4[1];
    acc[0] += xv * a.x; acc[1] += xv * a.y; acc[2] += xv * a.z; acc[3] += xv * a.w;
    acc[4] += xv * b.x; acc[5] += xv * b.y; acc[6] += xv * b.z; acc[7] += xv * b.w;
  }
#pragma unroll
  for (int off = 32; off >= 1; off >>= 1) {
#pragma unroll
    for (int e = 0; e < E_NUM; ++e) acc[e] += __shfl_xor(acc[e], off, 64);
  }
  if (lane == 0) {
    float v[E_NUM], mx = -1e30f;
#pragma unroll
    for (int e = 0; e < E_NUM; ++e) { v[e] = acc[e] + gb[e]; mx = fmaxf(mx, v[e]); }
    float s = 0.f;
#pragma unroll
    for (int e = 0; e < E_NUM; ++e) { v[e] = expf(v[e] - mx); s += v[e]; }
    const float inv = 1.f / s;
#pragma unroll
    for (int e = 0; e < E_NUM; ++e) gate[(size_t)row * E_NUM + e] = v[e] * inv;
  }
}

__global__ __launch_bounds__(256) void wtrans_kernel(const float* __restrict__ w,
                                                     unsigned short* __restrict__ wt) {
  __shared__ float tile[64][65];
  const int e  = blockIdx.z;
  const int p0 = blockIdx.y * 64;
  const int d0 = blockIdx.x * 64;
  const int tx = threadIdx.x & 63;
  const int ty = threadIdx.x >> 6;
  const float* src = w + ((size_t)e * D_DIM + d0) * P_DIM + p0;
#pragma unroll
  for (int i = 0; i < 16; ++i) {
    const int dr = i * 4 + ty;
    tile[dr][tx] = src[(size_t)dr * P_DIM + tx];
  }
  __syncthreads();
  unsigned short* dst = wt + ((size_t)e * P_DIM + p0) * D_DIM + d0;
#pragma unroll
  for (int i = 0; i < 16; ++i) {
    const int pr = i * 4 + ty;
    const int cc = tx ^ ((pr & 7) << 3);
    dst[(size_t)pr * D_DIM + cc] = f2bf(tile[tx][pr]);
  }
}

__global__ __launch_bounds__(256, 2) void moe_gemm_kernel(
    const float* __restrict__ x,
    const unsigned short* __restrict__ wt,
    const float* __restrict__ gate,
    const float* __restrict__ eb,
    float* __restrict__ out) {
  __shared__ unsigned short lA[128 * 64];
  __shared__ unsigned short lB[128 * 64];
  __shared__ float lG[128 * 8];
  __shared__ float lBias[E_NUM * 128];

  const int tid  = threadIdx.x;
  const int lane = tid & 63;
  const int wid  = tid >> 6;
  const int wr   = wid >> 1, wc = wid & 1;
  const int m0   = blockIdx.x * 128;
  const int n0   = blockIdx.y * 128;

  reinterpret_cast<float4*>(lG)[tid] =
      reinterpret_cast<const float4*>(gate + (size_t)m0 * E_NUM)[tid];
  {
    const int e = tid >> 5, cc = (tid & 31) * 4;
    *reinterpret_cast<float4*>(&lBias[e * 128 + cc]) =
        *reinterpret_cast<const float4*>(&eb[(size_t)e * P_DIM + n0 + cc]);
  }
  __syncthreads();

  const int rA   = tid >> 1;
  const int colA = (tid & 1) * 32;
  const float* xrow = x + (size_t)(m0 + rA) * D_DIM + colA;

  f32x4 acc[4][4];
#pragma unroll
  for (int i = 0; i < 4; ++i)
#pragma unroll
    for (int jj = 0; jj < 4; ++jj)
#pragma unroll
      for (int k = 0; k < 4; ++k) acc[i][jj][k] = 0.f;

  for (int e = 0; e < E_NUM; ++e) {
    const float gs = lG[rA * 8 + e];
    const unsigned short* wte = wt + ((size_t)e * P_DIM + n0) * D_DIM;
    for (int kt = 0; kt < 16; ++kt) {
      __syncthreads();
      const float4* apv = reinterpret_cast<const float4*>(xrow + kt * 64);
#pragma unroll
      for (int jj = 0; jj < 4; ++jj) {
        float4 p = apv[2 * jj], q = apv[2 * jj + 1];
        u16x8 v;
        v[0] = f2bf(p.x * gs); v[1] = f2bf(p.y * gs);
        v[2] = f2bf(p.z * gs); v[3] = f2bf(p.w * gs);
        v[4] = f2bf(q.x * gs); v[5] = f2bf(q.y * gs);
        v[6] = f2bf(q.z * gs); v[7] = f2bf(q.w * gs);
        const int idxw = rA * 64 + ((colA + jj * 8) ^ ((rA & 7) << 3));
        *reinterpret_cast<u16x8*>(&lA[idxw]) = v;
      }
#pragma unroll
      for (int i = 0; i < 4; ++i) {
        const int u  = tid + i * 256;
        const int rr = u >> 3;
        const int cc = u & 7;
        const unsigned short* src = wte + (size_t)rr * D_DIM + kt * 64 + cc * 8;
        __builtin_amdgcn_global_load_lds(
            (const __attribute__((address_space(1))) void*)src,
            (__attribute__((address_space(3))) void*)&lB[u * 8], 16, 0, 0);
      }
      __syncthreads();
#pragma unroll
      for (int kk = 0; kk < 2; ++kk) {
        const int e0 = kk * 32 + (lane >> 4) * 8;
        short8 a[4], b[4];
#pragma unroll
        for (int m = 0; m < 4; ++m) {
          const int r = wr * 64 + m * 16 + (lane & 15);
          a[m] = *reinterpret_cast<const short8*>(&lA[r * 64 + (e0 ^ ((r & 7) << 3))]);
        }
#pragma unroll
        for (int n = 0; n < 4; ++n) {
          const int r = wc * 64 + n * 16 + (lane & 15);
          b[n] = *reinterpret_cast<const short8*>(&lB[r * 64 + (e0 ^ ((r & 7) << 3))]);
        }
#pragma unroll
        for (int m = 0; m < 4; ++m)
#pragma unroll
          for (int n = 0; n < 4; ++n)
            acc[m][n] = __builtin_amdgcn_mfma_f32_16x16x32_bf16(a[m], b[n], acc[m][n], 0, 0, 0);
      }
    }
  }

#pragma unroll
  for (int m = 0; m < 4; ++m) {
#pragma unroll
    for (int n = 0; n < 4; ++n) {
      const int rbase = wr * 64 + m * 16 + ((lane >> 4) * 4);
      const int cl    = wc * 64 + n * 16 + (lane & 15);
#pragma unroll
      for (int reg = 0; reg < 4; ++reg) {
        const int r = rbase + reg;
        float bsum = 0.f;
#pragma unroll
        for (int e = 0; e < E_NUM; ++e) bsum += lG[r * 8 + e] * lBias[e * 128 + cl];
        out[(size_t)(m0 + r) * P_DIM + n0 + cl] = acc[m][n][reg] + bsum;
      }
    }
  }
}

// ============================ launch ============================

extern "C" void kernel_launch(void* const* d_in, const int* in_sizes, int n_in,
                              void* d_out, int out_size, void* d_ws, size_t ws_size,
                              hipStream_t stream) {
  const float* x  = (const float*)d_in[0];
  const float* gw = (const float*)d_in[1];
  const float* gb = (const float*)d_in[2];
  const float* ew = (const float*)d_in[3];
  const float* eb = (const float*)d_in[4];
  float* out = (float*)d_out;

  char* ws = (char*)d_ws;
  float* gate        = (float*)ws;                     // 256 KiB
  unsigned short* wt = (unsigned short*)(ws + 262144); // 16 MiB

  const size_t need_new = 262144ull + 16777216ull + 16777216ull;  // gate + wt + xb

  if (ws_size >= need_new) {
    unsigned short* xbb = (unsigned short*)(ws + 262144 + 16777216);  // 16 MiB
    prep_all_kernel<<<4096, 256, 0, stream>>>(x, gw, gb, ew, eb, gate, xbb, wt, out);
    gemm_8ph_kernel<<<256, 512, 0, stream>>>(xbb, wt, gate, out);
  } else {
    gate_kernel<<<M_TOT / 4, 256, 0, stream>>>(x, gw, gb, gate);
    wtrans_kernel<<<dim3(D_DIM / 64, P_DIM / 64, E_NUM), 256, 0, stream>>>(ew, wt);
    moe_gemm_kernel<<<dim3(M_TOT / 128, P_DIM / 128), 256, 0, stream>>>(x, wt, gate, eb, out);
  }
}

// Round 19
// 189.012 us; speedup vs baseline: 1.0902x; 1.0902x over previous
//
#include <hip/hip_runtime.h>
#include <hip/hip_bf16.h>
#include <math.h>

#define M_TOT 8192
#define D_DIM 1024
#define E_NUM 8
#define P_DIM 1024
#define K_TOT (E_NUM * D_DIM)  // 8192

typedef __attribute__((ext_vector_type(8))) short short8;
typedef __attribute__((ext_vector_type(4))) float f32x4;
typedef __attribute__((ext_vector_type(8))) unsigned short u16x8;

// round-to-nearest-even f32 -> bf16 (finite inputs)
static __device__ __forceinline__ unsigned short f2bf(float f) {
  unsigned u = __builtin_bit_cast(unsigned, f);
  unsigned r = (u + 0x7fffu + ((u >> 16) & 1u)) >> 16;
  return (unsigned short)r;
}

// ---- merged prep: blocks [0,2048) = per-row gate+xb+bias-init; [2048,4096) = W-transpose tiles ----
__global__ __launch_bounds__(256) void prep_all_kernel(const float* __restrict__ x,
                                                       const float* __restrict__ gw,
                                                       const float* __restrict__ gb,
                                                       const float* __restrict__ ew,
                                                       const float* __restrict__ eb,
                                                       float* __restrict__ gate,
                                                       unsigned short* __restrict__ xb,
                                                       unsigned short* __restrict__ wt,
                                                       float* __restrict__ out) {
  __shared__ __align__(16) unsigned short lx[4][1024];  // 8 KB   (prep path)
  __shared__ float tile[64][65];                        // 16.25 KB (wtrans path)

  if (blockIdx.x < 2048) {
    // ================= per-row prep =================
    const int wv   = threadIdx.x >> 6;
    const int lane = threadIdx.x & 63;
    const int row  = blockIdx.x * 4 + wv;
    const float* xr = x + (size_t)row * D_DIM;

    float acc[E_NUM];
#pragma unroll
    for (int e = 0; e < E_NUM; ++e) acc[e] = 0.f;
#pragma unroll
    for (int it = 0; it < 16; ++it) {
      const int d = it * 64 + lane;
      const float xv = xr[d];
      lx[wv][d] = f2bf(xv);
      const float4* g4 = reinterpret_cast<const float4*>(gw + (size_t)d * E_NUM);
      const float4 a = g4[0], b = g4[1];
      acc[0] += xv * a.x; acc[1] += xv * a.y; acc[2] += xv * a.z; acc[3] += xv * a.w;
      acc[4] += xv * b.x; acc[5] += xv * b.y; acc[6] += xv * b.z; acc[7] += xv * b.w;
    }
#pragma unroll
    for (int off = 32; off >= 1; off >>= 1) {
#pragma unroll
      for (int e = 0; e < E_NUM; ++e) acc[e] += __shfl_xor(acc[e], off, 64);
    }
    __syncthreads();  // publish LDS bf16 row

    float g[E_NUM], mx = -1e30f;
#pragma unroll
    for (int e = 0; e < E_NUM; ++e) { g[e] = acc[e] + gb[e]; mx = fmaxf(mx, g[e]); }
    float s = 0.f;
#pragma unroll
    for (int e = 0; e < E_NUM; ++e) { g[e] = expf(g[e] - mx); s += g[e]; }
    const float inv = 1.f / s;
#pragma unroll
    for (int e = 0; e < E_NUM; ++e) g[e] *= inv;
    if (lane == 0) {
#pragma unroll
      for (int e = 0; e < E_NUM; ++e) gate[(size_t)row * E_NUM + e] = g[e];
    }

    // xb: two swizzled 16B chunks per lane, sourced from LDS (contiguous)
    unsigned short* xrow = xb + (size_t)row * D_DIM;
#pragma unroll
    for (int h = 0; h < 2; ++h) {
      const int jd = lane * 2 + h;
      const int cbase = (jd >> 3) * 8 + ((jd & 7) ^ (row & 7));
      const u16x8 vv = *reinterpret_cast<const u16x8*>(&lx[wv][jd * 8]);
      *reinterpret_cast<u16x8*>(&xrow[cbase * 8]) = vv;
    }

    // bias-init: out[row][p] = sum_e g[e]*eb[e][p], coalesced float4 per lane
    float* orow = out + (size_t)row * P_DIM;
#pragma unroll
    for (int q = 0; q < 4; ++q) {
      const int p = q * 256 + lane * 4;
      float4 sv = {0.f, 0.f, 0.f, 0.f};
#pragma unroll
      for (int e = 0; e < E_NUM; ++e) {
        const float4 b4 = *reinterpret_cast<const float4*>(&eb[(size_t)e * P_DIM + p]);
        sv.x += g[e] * b4.x; sv.y += g[e] * b4.y; sv.z += g[e] * b4.z; sv.w += g[e] * b4.w;
      }
      *reinterpret_cast<float4*>(&orow[p]) = sv;
    }
  } else {
    // ================= W [E][D][P] f32 -> wt [P][E*D] bf16, swizzle baked =================
    const int bid2 = blockIdx.x - 2048;            // 0..2047 = d0idx + 16*p0idx + 256*e
    const int e  = bid2 >> 8;
    const int p0 = ((bid2 >> 4) & 15) * 64;
    const int d0 = (bid2 & 15) * 64;
    const int tx = threadIdx.x & 63;
    const int ty = threadIdx.x >> 6;
    const float* src = ew + ((size_t)e * D_DIM + d0) * P_DIM + p0;
#pragma unroll
    for (int i = 0; i < 16; ++i) {
      const int dr = i * 4 + ty;
      tile[dr][tx] = src[(size_t)dr * P_DIM + tx];
    }
    __syncthreads();
    // vectorized swizzled stores: 512 (pr,chunk) pairs, one u16x8 each.
#pragma unroll
    for (int h = 0; h < 2; ++h) {
      const int u  = threadIdx.x + h * 256;  // 0..511
      const int pr = u >> 3;                 // 0..63
      const int ch = u & 7;                  // source chunk
      u16x8 v;
#pragma unroll
      for (int j = 0; j < 8; ++j) v[j] = f2bf(tile[ch * 8 + j][pr]);
      const int cs = ch ^ (pr & 7);
      *reinterpret_cast<u16x8*>(&wt[(size_t)(p0 + pr) * K_TOT + e * D_DIM + d0 + cs * 8]) = v;
    }
  }
}

// ---- Horner-gated expert-loop GEMM: 128x128 tile, BK=64, 4 waves, split-K=2 over expert halves ----
__global__ __launch_bounds__(256, 3) void gemm_ex2_kernel(
    const unsigned short* __restrict__ xb,
    const unsigned short* __restrict__ wt,
    const float* __restrict__ gate,
    float* __restrict__ out) {
  __shared__ unsigned short lA[128 * 64];   // 16 KB
  __shared__ unsigned short lB[128 * 64];   // 16 KB
  __shared__ float lG[128 * 8];             // 4 KB  -> 36 KB total

  const int tid  = threadIdx.x;
  const int lane = tid & 63;
  const int wid  = tid >> 6;
  const int wr   = wid >> 1, wc = wid & 1;

  // 1024 blocks: xcd = bid&7 = nt (2MB wt slice L2-resident); idx: kh = idx&1, mt = idx>>1.
  const int bid = blockIdx.x;
  const int nt  = bid & 7;
  const int idx = bid >> 3;
  const int kh  = idx & 1;
  const int mt  = idx >> 1;
  const int m0  = mt * 128, n0 = nt * 128;

  reinterpret_cast<float4*>(lG)[tid] =
      reinterpret_cast<const float4*>(gate + (size_t)m0 * E_NUM)[tid];

  f32x4 acc[4][4];
#pragma unroll
  for (int i = 0; i < 4; ++i)
#pragma unroll
    for (int j = 0; j < 4; ++j)
#pragma unroll
      for (int k = 0; k < 4; ++k) acc[i][j][k] = 0.f;

  const int r0 = tid >> 3;  // 0..31
  const int c8 = tid & 7;   // 16B chunk within 64-short block
  const unsigned short* pAb = xb + (size_t)(m0 + r0) * D_DIM + c8 * 8;
  const unsigned short* pBb = wt + (size_t)(n0 + r0) * K_TOT + c8 * 8;

  for (int e = 0; e < 4; ++e) {
    const int eg = kh * 4 + e;
    if (e > 0) {
      // Horner rescale: acc *= g[row][eg-1] / g[row][eg]  (softmax gates bounded below, safe)
#pragma unroll
      for (int m = 0; m < 4; ++m) {
#pragma unroll
        for (int reg = 0; reg < 4; ++reg) {
          const int r = wr * 64 + m * 16 + (lane >> 4) * 4 + reg;
          const float ratio = lG[r * 8 + (eg - 1)] / lG[r * 8 + eg];
#pragma unroll
          for (int n = 0; n < 4; ++n) acc[m][n][reg] *= ratio;
        }
      }
    }
    const unsigned short* pB = pBb + (size_t)eg * D_DIM;
    for (int kt = 0; kt < 16; ++kt) {
      __syncthreads();  // previous tile's LDS reads complete
#pragma unroll
      for (int i = 0; i < 4; ++i) {
        __builtin_amdgcn_global_load_lds(
            (const __attribute__((address_space(1))) void*)(pAb + (size_t)i * 32 * D_DIM + kt * 64),
            (__attribute__((address_space(3))) void*)&lA[(tid + i * 256) * 8], 16, 0, 0);
      }
#pragma unroll
      for (int i = 0; i < 4; ++i) {
        __builtin_amdgcn_global_load_lds(
            (const __attribute__((address_space(1))) void*)(pB + (size_t)i * 32 * K_TOT + kt * 64),
            (__attribute__((address_space(3))) void*)&lB[(tid + i * 256) * 8], 16, 0, 0);
      }
      __syncthreads();  // compiler drains vmcnt before barrier
#pragma unroll
      for (int kk = 0; kk < 2; ++kk) {
        const int e0 = kk * 32 + (lane >> 4) * 8;
        short8 a[4], b[4];
#pragma unroll
        for (int m = 0; m < 4; ++m) {
          const int r = wr * 64 + m * 16 + (lane & 15);
          a[m] = *reinterpret_cast<const short8*>(&lA[r * 64 + (e0 ^ ((r & 7) << 3))]);
        }
#pragma unroll
        for (int n = 0; n < 4; ++n) {
          const int r = wc * 64 + n * 16 + (lane & 15);
          b[n] = *reinterpret_cast<const short8*>(&lB[r * 64 + (e0 ^ ((r & 7) << 3))]);
        }
#pragma unroll
        for (int m = 0; m < 4; ++m)
#pragma unroll
          for (int n = 0; n < 4; ++n)
            acc[m][n] = __builtin_amdgcn_mfma_f32_16x16x32_bf16(a[m], b[n], acc[m][n], 0, 0, 0);
      }
    }
  }

  // ---- epilogue: final Horner scale by g[row][kh*4+3]; atomic accumulate (bias pre-initialized) ----
#pragma unroll
  for (int n = 0; n < 4; ++n) {
    const int cl = wc * 64 + n * 16 + (lane & 15);
#pragma unroll
    for (int m = 0; m < 4; ++m) {
#pragma unroll
      for (int reg = 0; reg < 4; ++reg) {
        const int r  = wr * 64 + m * 16 + (lane >> 4) * 4 + reg;
        const float gl = lG[r * 8 + kh * 4 + 3];
        atomicAdd(&out[(size_t)(m0 + r) * P_DIM + n0 + cl], acc[m][n][reg] * gl);
      }
    }
  }
}

// ============================ FALLBACK PATH (round-2, passing) ============================

__global__ __launch_bounds__(256) void gate_kernel(const float* __restrict__ x,
                                                   const float* __restrict__ gw,
                                                   const float* __restrict__ gb,
                                                   float* __restrict__ gate) {
  const int row  = blockIdx.x * 4 + (threadIdx.x >> 6);
  const int lane = threadIdx.x & 63;
  const float* xr = x + (size_t)row * D_DIM;
  float acc[E_NUM];
#pragma unroll
  for (int e = 0; e < E_NUM; ++e) acc[e] = 0.f;
#pragma unroll
  for (int it = 0; it < 16; ++it) {
    const int d = it * 64 + lane;
    const float xv = xr[d];
    const float4* g4 = reinterpret_cast<const float4*>(gw + (size_t)d * E_NUM);
    float4 a = g4[0], b = g4[1];
    acc[0] += xv * a.x; acc[1] += xv * a.y; acc[2] += xv * a.z; acc[3] += xv * a.w;
    acc[4] += xv * b.x; acc[5] += xv * b.y; acc[6] += xv * b.z; acc[7] += xv * b.w;
  }
#pragma unroll
  for (int off = 32; off >= 1; off >>= 1) {
#pragma unroll
    for (int e = 0; e < E_NUM; ++e) acc[e] += __shfl_xor(acc[e], off, 64);
  }
  if (lane == 0) {
    float v[E_NUM], mx = -1e30f;
#pragma unroll
    for (int e = 0; e < E_NUM; ++e) { v[e] = acc[e] + gb[e]; mx = fmaxf(mx, v[e]); }
    float s = 0.f;
#pragma unroll
    for (int e = 0; e < E_NUM; ++e) { v[e] = expf(v[e] - mx); s += v[e]; }
    const float inv = 1.f / s;
#pragma unroll
    for (int e = 0; e < E_NUM; ++e) gate[(size_t)row * E_NUM + e] = v[e] * inv;
  }
}

__global__ __launch_bounds__(256) void wtrans_kernel(const float* __restrict__ w,
                                                     unsigned short* __restrict__ wt) {
  __shared__ float tile[64][65];
  const int e  = blockIdx.z;
  const int p0 = blockIdx.y * 64;
  const int d0 = blockIdx.x * 64;
  const int tx = threadIdx.x & 63;
  const int ty = threadIdx.x >> 6;
  const float* src = w + ((size_t)e * D_DIM + d0) * P_DIM + p0;
#pragma unroll
  for (int i = 0; i < 16; ++i) {
    const int dr = i * 4 + ty;
    tile[dr][tx] = src[(size_t)dr * P_DIM + tx];
  }
  __syncthreads();
  unsigned short* dst = wt + ((size_t)e * P_DIM + p0) * D_DIM + d0;
#pragma unroll
  for (int i = 0; i < 16; ++i) {
    const int pr = i * 4 + ty;
    const int cc = tx ^ ((pr & 7) << 3);
    dst[(size_t)pr * D_DIM + cc] = f2bf(tile[tx][pr]);
  }
}

__global__ __launch_bounds__(256, 2) void moe_gemm_kernel(
    const float* __restrict__ x,
    const unsigned short* __restrict__ wt,
    const float* __restrict__ gate,
    const float* __restrict__ eb,
    float* __restrict__ out) {
  __shared__ unsigned short lA[128 * 64];
  __shared__ unsigned short lB[128 * 64];
  __shared__ float lG[128 * 8];
  __shared__ float lBias[E_NUM * 128];

  const int tid  = threadIdx.x;
  const int lane = tid & 63;
  const int wid  = tid >> 6;
  const int wr   = wid >> 1, wc = wid & 1;
  const int m0   = blockIdx.x * 128;
  const int n0   = blockIdx.y * 128;

  reinterpret_cast<float4*>(lG)[tid] =
      reinterpret_cast<const float4*>(gate + (size_t)m0 * E_NUM)[tid];
  {
    const int e = tid >> 5, cc = (tid & 31) * 4;
    *reinterpret_cast<float4*>(&lBias[e * 128 + cc]) =
        *reinterpret_cast<const float4*>(&eb[(size_t)e * P_DIM + n0 + cc]);
  }
  __syncthreads();

  const int rA   = tid >> 1;
  const int colA = (tid & 1) * 32;
  const float* xrow = x + (size_t)(m0 + rA) * D_DIM + colA;

  f32x4 acc[4][4];
#pragma unroll
  for (int i = 0; i < 4; ++i)
#pragma unroll
    for (int jj = 0; jj < 4; ++jj)
#pragma unroll
      for (int k = 0; k < 4; ++k) acc[i][jj][k] = 0.f;

  for (int e = 0; e < E_NUM; ++e) {
    const float gs = lG[rA * 8 + e];
    const unsigned short* wte = wt + ((size_t)e * P_DIM + n0) * D_DIM;
    for (int kt = 0; kt < 16; ++kt) {
      __syncthreads();
      const float4* apv = reinterpret_cast<const float4*>(xrow + kt * 64);
#pragma unroll
      for (int jj = 0; jj < 4; ++jj) {
        float4 p = apv[2 * jj], q = apv[2 * jj + 1];
        u16x8 v;
        v[0] = f2bf(p.x * gs); v[1] = f2bf(p.y * gs);
        v[2] = f2bf(p.z * gs); v[3] = f2bf(p.w * gs);
        v[4] = f2bf(q.x * gs); v[5] = f2bf(q.y * gs);
        v[6] = f2bf(q.z * gs); v[7] = f2bf(q.w * gs);
        const int idxw = rA * 64 + ((colA + jj * 8) ^ ((rA & 7) << 3));
        *reinterpret_cast<u16x8*>(&lA[idxw]) = v;
      }
#pragma unroll
      for (int i = 0; i < 4; ++i) {
        const int u  = tid + i * 256;
        const int rr = u >> 3;
        const int cc = u & 7;
        const unsigned short* src = wte + (size_t)rr * D_DIM + kt * 64 + cc * 8;
        __builtin_amdgcn_global_load_lds(
            (const __attribute__((address_space(1))) void*)src,
            (__attribute__((address_space(3))) void*)&lB[u * 8], 16, 0, 0);
      }
      __syncthreads();
#pragma unroll
      for (int kk = 0; kk < 2; ++kk) {
        const int e0 = kk * 32 + (lane >> 4) * 8;
        short8 a[4], b[4];
#pragma unroll
        for (int m = 0; m < 4; ++m) {
          const int r = wr * 64 + m * 16 + (lane & 15);
          a[m] = *reinterpret_cast<const short8*>(&lA[r * 64 + (e0 ^ ((r & 7) << 3))]);
        }
#pragma unroll
        for (int n = 0; n < 4; ++n) {
          const int r = wc * 64 + n * 16 + (lane & 15);
          b[n] = *reinterpret_cast<const short8*>(&lB[r * 64 + (e0 ^ ((r & 7) << 3))]);
        }
#pragma unroll
        for (int m = 0; m < 4; ++m)
#pragma unroll
          for (int n = 0; n < 4; ++n)
            acc[m][n] = __builtin_amdgcn_mfma_f32_16x16x32_bf16(a[m], b[n], acc[m][n], 0, 0, 0);
      }
    }
  }

#pragma unroll
  for (int m = 0; m < 4; ++m) {
#pragma unroll
    for (int n = 0; n < 4; ++n) {
      const int rbase = wr * 64 + m * 16 + ((lane >> 4) * 4);
      const int cl    = wc * 64 + n * 16 + (lane & 15);
#pragma unroll
      for (int reg = 0; reg < 4; ++reg) {
        const int r = rbase + reg;
        float bsum = 0.f;
#pragma unroll
        for (int e = 0; e < E_NUM; ++e) bsum += lG[r * 8 + e] * lBias[e * 128 + cl];
        out[(size_t)(m0 + r) * P_DIM + n0 + cl] = acc[m][n][reg] + bsum;
      }
    }
  }
}

// ============================ launch ============================

extern "C" void kernel_launch(void* const* d_in, const int* in_sizes, int n_in,
                              void* d_out, int out_size, void* d_ws, size_t ws_size,
                              hipStream_t stream) {
  const float* x  = (const float*)d_in[0];
  const float* gw = (const float*)d_in[1];
  const float* gb = (const float*)d_in[2];
  const float* ew = (const float*)d_in[3];
  const float* eb = (const float*)d_in[4];
  float* out = (float*)d_out;

  char* ws = (char*)d_ws;
  float* gate        = (float*)ws;                     // 256 KiB
  unsigned short* wt = (unsigned short*)(ws + 262144); // 16 MiB

  const size_t need_new = 262144ull + 16777216ull + 16777216ull;  // gate + wt + xb

  if (ws_size >= need_new) {
    unsigned short* xbb = (unsigned short*)(ws + 262144 + 16777216);  // 16 MiB
    prep_all_kernel<<<4096, 256, 0, stream>>>(x, gw, gb, ew, eb, gate, xbb, wt, out);
    gemm_ex2_kernel<<<1024, 256, 0, stream>>>(xbb, wt, gate, out);
  } else {
    gate_kernel<<<M_TOT / 4, 256, 0, stream>>>(x, gw, gb, gate);
    wtrans_kernel<<<dim3(D_DIM / 64, P_DIM / 64, E_NUM), 256, 0, stream>>>(ew, wt);
    moe_gemm_kernel<<<dim3(M_TOT / 128, P_DIM / 128), 256, 0, stream>>>(x, wt, gate, eb, out);
  }
}